// Round 1
// baseline (287.798 us; speedup 1.0000x reference)
//
#include <hip/hip_runtime.h>
#include <cstdint>

#define N_TOK 4096
#define DMODEL 512
#define NHEADS 8
#define HDIM 64

typedef unsigned short u16;
typedef __bf16 bf16x8 __attribute__((ext_vector_type(8)));
typedef float f32x4 __attribute__((ext_vector_type(4)));

union U128 { uint4 u; bf16x8 b; u16 s[8]; };

__device__ __forceinline__ u16 f2bf(float f) {
  uint32_t u = __builtin_bit_cast(uint32_t, f);
  u += 0x7FFFu + ((u >> 16) & 1u);
  return (u16)(u >> 16);
}
__device__ __forceinline__ float bf2f(u16 s) {
  uint32_t u = ((uint32_t)s) << 16;
  return __builtin_bit_cast(float, u);
}

// ---------------------------------------------------------------------------
// Kernel 1: fused QKV projection.  Y[n][j] = bf16( sum_d X[n][d]*W[j][d] + b[j] )
// grid (64 m-tiles, 8 j-tiles, 3 matrices), block 256 (4 waves)
// ---------------------------------------------------------------------------
__global__ __launch_bounds__(256) void proj3_kernel(
    const float* __restrict__ Qin, const float* __restrict__ Kin, const float* __restrict__ Vin,
    const float* __restrict__ WQ, const float* __restrict__ WK, const float* __restrict__ WV,
    const float* __restrict__ bQ, const float* __restrict__ bK, const float* __restrict__ bV,
    u16* __restrict__ Qs, u16* __restrict__ Ks, u16* __restrict__ Vs)
{
  const int z = blockIdx.z;
  const float* A    = (z == 0) ? Qin : (z == 1) ? Kin : Vin;
  const float* W    = (z == 0) ? WQ  : (z == 1) ? WK  : WV;
  const float* bias = (z == 0) ? bQ  : (z == 1) ? bK  : bV;
  u16* Y            = (z == 0) ? Qs  : (z == 1) ? Ks  : Vs;

  const int m0 = blockIdx.x * 64;
  const int j0 = blockIdx.y * 64;
  const int tid = threadIdx.x;
  const int w = tid >> 6, lane = tid & 63, quad = lane >> 4, l = lane & 15;

  __shared__ bf16x8 sA[4][64];   // [k-chunk of 8][row]
  __shared__ bf16x8 sB[4][64];

  const f32x4 zero = {0.f, 0.f, 0.f, 0.f};
  f32x4 acc[4];
  for (int s = 0; s < 4; ++s) acc[s] = zero;

  const int srow = tid >> 2;   // 0..63
  const int scc  = tid & 3;    // 0..3

  for (int k0 = 0; k0 < DMODEL; k0 += 32) {
    __syncthreads();
    {
      const float* p = A + (size_t)(m0 + srow) * DMODEL + k0 + scc * 8;
      float4 f0 = *(const float4*)p;
      float4 f1 = *(const float4*)(p + 4);
      U128 u;
      u.s[0]=f2bf(f0.x); u.s[1]=f2bf(f0.y); u.s[2]=f2bf(f0.z); u.s[3]=f2bf(f0.w);
      u.s[4]=f2bf(f1.x); u.s[5]=f2bf(f1.y); u.s[6]=f2bf(f1.z); u.s[7]=f2bf(f1.w);
      sA[scc][srow] = u.b;
      const float* pw = W + (size_t)(j0 + srow) * DMODEL + k0 + scc * 8;
      float4 g0 = *(const float4*)pw;
      float4 g1 = *(const float4*)(pw + 4);
      U128 v;
      v.s[0]=f2bf(g0.x); v.s[1]=f2bf(g0.y); v.s[2]=f2bf(g0.z); v.s[3]=f2bf(g0.w);
      v.s[4]=f2bf(g1.x); v.s[5]=f2bf(g1.y); v.s[6]=f2bf(g1.z); v.s[7]=f2bf(g1.w);
      sB[scc][srow] = v.b;
    }
    __syncthreads();
    bf16x8 af = sA[quad][w * 16 + l];
#pragma unroll
    for (int s = 0; s < 4; ++s) {
      bf16x8 bfb = sB[quad][s * 16 + l];
      acc[s] = __builtin_amdgcn_mfma_f32_16x16x32_bf16(af, bfb, acc[s], 0, 0, 0);
    }
  }
#pragma unroll
  for (int s = 0; s < 4; ++s) {
    int j = j0 + s * 16 + l;
    float bv = bias[j];
#pragma unroll
    for (int r = 0; r < 4; ++r) {
      int n = m0 + w * 16 + quad * 4 + r;
      Y[(size_t)n * DMODEL + j] = f2bf(acc[s][r] + bv);
    }
  }
}

// ---------------------------------------------------------------------------
// Kernel 2: per-head transpose Vs[n][h*64+vd] -> Vt[h][vd][n]
// grid (64 n-tiles, 8 heads), block 256
// ---------------------------------------------------------------------------
__global__ __launch_bounds__(256) void transpose_v_kernel(
    const u16* __restrict__ Vs, u16* __restrict__ Vt)
{
  const int h = blockIdx.y, n0 = blockIdx.x * 64;
  const int tid = threadIdx.x;
  __shared__ u16 tile[64 * 65];
#pragma unroll
  for (int i = 0; i < 2; ++i) {
    int idx = tid + 256 * i;          // 0..511
    int r = idx >> 3, cc = idx & 7;
    U128 u;
    u.u = *(const uint4*)(Vs + (size_t)(n0 + r) * DMODEL + h * HDIM + cc * 8);
#pragma unroll
    for (int j = 0; j < 8; ++j) tile[r * 65 + cc * 8 + j] = u.s[j];
  }
  __syncthreads();
#pragma unroll
  for (int i = 0; i < 2; ++i) {
    int idx = tid + 256 * i;
    int vd = idx >> 3, nc = idx & 7;
    U128 u;
#pragma unroll
    for (int j = 0; j < 8; ++j) u.s[j] = tile[(nc * 8 + j) * 65 + vd];
    *(uint4*)(Vt + (size_t)h * HDIM * N_TOK + (size_t)vd * N_TOK + n0 + nc * 8) = u.u;
  }
}

// ---------------------------------------------------------------------------
// Kernel 3: flash attention.  Block = 64 queries x 1 head, 4 waves x 16 rows.
// grid (64 q-tiles, 8 heads), block 256
// ---------------------------------------------------------------------------
__global__ __launch_bounds__(256) void attn_kernel(
    const u16* __restrict__ Qs, const u16* __restrict__ Ks,
    const u16* __restrict__ Vt, u16* __restrict__ ctx)
{
  const int h = blockIdx.y;
  const int q0 = blockIdx.x * 64;
  const int tid = threadIdx.x;
  const int w = tid >> 6, lane = tid & 63, quad = lane >> 4, l = lane & 15;

  __shared__ bf16x8 kch[8][64];                    // [d-chunk][key]
  __shared__ bf16x8 vch[8][64];                    // [key-chunk][vd]
  __shared__ __align__(16) u16 pbuf[4][8][16][8];  // [wave][key-chunk][q][off]

  // Q fragments (A-operand layout), pre-scaled by 1/sqrt(64) = 0.125
  bf16x8 qf[2];
#pragma unroll
  for (int c = 0; c < 2; ++c) {
    U128 u;
    u.u = *(const uint4*)(Qs + (size_t)(q0 + w * 16 + l) * DMODEL + h * HDIM + c * 32 + quad * 8);
#pragma unroll
    for (int j = 0; j < 8; ++j) u.s[j] = f2bf(bf2f(u.s[j]) * 0.125f);
    qf[c] = u.b;
  }

  const f32x4 zero = {0.f, 0.f, 0.f, 0.f};
  float m_r[4], l_r[4];
  f32x4 o[4];
#pragma unroll
  for (int r = 0; r < 4; ++r) { m_r[r] = -1e30f; l_r[r] = 0.f; }
#pragma unroll
  for (int s = 0; s < 4; ++s) o[s] = zero;

  const int srow = tid >> 2;   // 0..63
  const int scc  = tid & 3;    // 0..3

  for (int j0 = 0; j0 < N_TOK; j0 += 64) {
    __syncthreads();
    {
      const u16* kp = Ks + (size_t)(j0 + srow) * DMODEL + h * HDIM;
      U128 u;
      u.u = *(const uint4*)(kp + scc * 8);        kch[scc][srow] = u.b;
      u.u = *(const uint4*)(kp + (scc + 4) * 8);  kch[scc + 4][srow] = u.b;
      const u16* vp = Vt + (size_t)h * HDIM * N_TOK + (size_t)srow * N_TOK + j0;
      u.u = *(const uint4*)(vp + scc * 8);        vch[scc][srow] = u.b;
      u.u = *(const uint4*)(vp + (scc + 4) * 8);  vch[scc + 4][srow] = u.b;
    }
    __syncthreads();

    // S = (Q/8) K^T   for 64 keys: 4 subtiles of 16 keys, contraction d=64 (2 chunks)
    f32x4 sacc[4];
#pragma unroll
    for (int t = 0; t < 4; ++t) {
      sacc[t] = zero;
#pragma unroll
      for (int c = 0; c < 2; ++c) {
        bf16x8 kf = kch[c * 4 + quad][t * 16 + l];
        sacc[t] = __builtin_amdgcn_mfma_f32_16x16x32_bf16(qf[c], kf, sacc[t], 0, 0, 0);
      }
    }

    // online softmax (rows live in 16-lane quad groups)
    float p[4][4];
#pragma unroll
    for (int r = 0; r < 4; ++r) {
      float tm = fmaxf(fmaxf(sacc[0][r], sacc[1][r]), fmaxf(sacc[2][r], sacc[3][r]));
      tm = fmaxf(tm, __shfl_xor(tm, 1));
      tm = fmaxf(tm, __shfl_xor(tm, 2));
      tm = fmaxf(tm, __shfl_xor(tm, 4));
      tm = fmaxf(tm, __shfl_xor(tm, 8));
      float mnew = fmaxf(m_r[r], tm);
      float alpha = __expf(m_r[r] - mnew);
      float rs = 0.f;
#pragma unroll
      for (int t = 0; t < 4; ++t) { p[t][r] = __expf(sacc[t][r] - mnew); rs += p[t][r]; }
      rs += __shfl_xor(rs, 1);
      rs += __shfl_xor(rs, 2);
      rs += __shfl_xor(rs, 4);
      rs += __shfl_xor(rs, 8);
      l_r[r] = alpha * l_r[r] + rs;
      m_r[r] = mnew;
#pragma unroll
      for (int s = 0; s < 4; ++s) o[s][r] *= alpha;
    }

    // P: C-layout -> A-layout via per-wave LDS
#pragma unroll
    for (int t = 0; t < 4; ++t) {
      int cc = 2 * t + (l >> 3);
      int off = l & 7;
#pragma unroll
      for (int r = 0; r < 4; ++r)
        pbuf[w][cc][quad * 4 + r][off] = f2bf(p[t][r]);
    }
    __syncthreads();

    // O += P V : contraction over 64 keys (2 chunks), 4 vd subtiles
#pragma unroll
    for (int c = 0; c < 2; ++c) {
      U128 u;
      u.u = *(const uint4*)&pbuf[w][c * 4 + quad][l][0];
      bf16x8 pf = u.b;
#pragma unroll
      for (int s = 0; s < 4; ++s) {
        bf16x8 vf = vch[c * 4 + quad][s * 16 + l];
        o[s] = __builtin_amdgcn_mfma_f32_16x16x32_bf16(pf, vf, o[s], 0, 0, 0);
      }
    }
  }

  // epilogue: ctx[n][h*64+vd] = O / l
#pragma unroll
  for (int r = 0; r < 4; ++r) {
    float inv = 1.f / l_r[r];
    int n = q0 + w * 16 + quad * 4 + r;
#pragma unroll
    for (int s = 0; s < 4; ++s)
      ctx[(size_t)n * DMODEL + h * HDIM + s * 16 + l] = f2bf(o[s][r] * inv);
  }
}

// ---------------------------------------------------------------------------
// Kernel 4: output projection + bias + residual.  tmp[n][j] = ctx@WO^T + bO + Q
// grid (64 m-tiles, 8 j-tiles), block 256
// ---------------------------------------------------------------------------
__global__ __launch_bounds__(256) void gemmo_kernel(
    const u16* __restrict__ ctx, const float* __restrict__ WO,
    const float* __restrict__ bO, const float* __restrict__ resid,
    float* __restrict__ Y)
{
  const int m0 = blockIdx.x * 64;
  const int j0 = blockIdx.y * 64;
  const int tid = threadIdx.x;
  const int w = tid >> 6, lane = tid & 63, quad = lane >> 4, l = lane & 15;

  __shared__ bf16x8 sA[4][64];
  __shared__ bf16x8 sB[4][64];

  const f32x4 zero = {0.f, 0.f, 0.f, 0.f};
  f32x4 acc[4];
  for (int s = 0; s < 4; ++s) acc[s] = zero;

  const int srow = tid >> 2;
  const int scc  = tid & 3;

  for (int k0 = 0; k0 < DMODEL; k0 += 32) {
    __syncthreads();
    {
      U128 u;
      u.u = *(const uint4*)(ctx + (size_t)(m0 + srow) * DMODEL + k0 + scc * 8);
      sA[scc][srow] = u.b;
      const float* pw = WO + (size_t)(j0 + srow) * DMODEL + k0 + scc * 8;
      float4 g0 = *(const float4*)pw;
      float4 g1 = *(const float4*)(pw + 4);
      U128 v;
      v.s[0]=f2bf(g0.x); v.s[1]=f2bf(g0.y); v.s[2]=f2bf(g0.z); v.s[3]=f2bf(g0.w);
      v.s[4]=f2bf(g1.x); v.s[5]=f2bf(g1.y); v.s[6]=f2bf(g1.z); v.s[7]=f2bf(g1.w);
      sB[scc][srow] = v.b;
    }
    __syncthreads();
    bf16x8 af = sA[quad][w * 16 + l];
#pragma unroll
    for (int s = 0; s < 4; ++s) {
      bf16x8 bfb = sB[quad][s * 16 + l];
      acc[s] = __builtin_amdgcn_mfma_f32_16x16x32_bf16(af, bfb, acc[s], 0, 0, 0);
    }
  }
#pragma unroll
  for (int s = 0; s < 4; ++s) {
    int j = j0 + s * 16 + l;
    float bv = bO[j];
#pragma unroll
    for (int r = 0; r < 4; ++r) {
      int n = m0 + w * 16 + quad * 4 + r;
      Y[(size_t)n * DMODEL + j] = acc[s][r] + bv + resid[(size_t)n * DMODEL + j];
    }
  }
}

// ---------------------------------------------------------------------------
// Kernel 5: LayerNorm per row.  One wave per row, 8 floats per lane.
// grid 1024, block 256 (4 waves)
// ---------------------------------------------------------------------------
__global__ __launch_bounds__(256) void ln_kernel(
    const float* __restrict__ X, const float* __restrict__ gamma,
    const float* __restrict__ beta, float* __restrict__ Y)
{
  const int w = threadIdx.x >> 6, lane = threadIdx.x & 63;
  const int row = blockIdx.x * 4 + w;
  const float* x = X + (size_t)row * DMODEL + lane * 8;
  float4 a = *(const float4*)x;
  float4 b = *(const float4*)(x + 4);

  float s = a.x + a.y + a.z + a.w + b.x + b.y + b.z + b.w;
#pragma unroll
  for (int m = 1; m < 64; m <<= 1) s += __shfl_xor(s, m);
  float mu = s * (1.f / DMODEL);

  float d0 = a.x - mu, d1 = a.y - mu, d2 = a.z - mu, d3 = a.w - mu;
  float d4 = b.x - mu, d5 = b.y - mu, d6 = b.z - mu, d7 = b.w - mu;
  float v = d0*d0 + d1*d1 + d2*d2 + d3*d3 + d4*d4 + d5*d5 + d6*d6 + d7*d7;
#pragma unroll
  for (int m = 1; m < 64; m <<= 1) v += __shfl_xor(v, m);
  float sc = rsqrtf(v * (1.f / DMODEL) + 1e-5f);

  const float* g = gamma + lane * 8;
  const float* be = beta + lane * 8;
  float4 go = *(const float4*)g;
  float4 g1 = *(const float4*)(g + 4);
  float4 bo = *(const float4*)be;
  float4 b1 = *(const float4*)(be + 4);

  float4 y0, y1;
  y0.x = d0 * sc * go.x + bo.x;  y0.y = d1 * sc * go.y + bo.y;
  y0.z = d2 * sc * go.z + bo.z;  y0.w = d3 * sc * go.w + bo.w;
  y1.x = d4 * sc * g1.x + b1.x;  y1.y = d5 * sc * g1.y + b1.y;
  y1.z = d6 * sc * g1.z + b1.z;  y1.w = d7 * sc * g1.w + b1.w;

  float* yp = Y + (size_t)row * DMODEL + lane * 8;
  *(float4*)yp = y0;
  *(float4*)(yp + 4) = y1;
}

// ---------------------------------------------------------------------------
extern "C" void kernel_launch(void* const* d_in, const int* in_sizes, int n_in,
                              void* d_out, int out_size, void* d_ws, size_t ws_size,
                              hipStream_t stream)
{
  const float* Q     = (const float*)d_in[0];
  const float* K     = (const float*)d_in[1];
  const float* V     = (const float*)d_in[2];
  const float* WQ    = (const float*)d_in[3];
  const float* bQ    = (const float*)d_in[4];
  const float* WK    = (const float*)d_in[5];
  const float* bK    = (const float*)d_in[6];
  const float* WV    = (const float*)d_in[7];
  const float* bV    = (const float*)d_in[8];
  const float* WO    = (const float*)d_in[9];
  const float* bO    = (const float*)d_in[10];
  const float* gamma = (const float*)d_in[11];
  const float* beta  = (const float*)d_in[12];

  char* ws = (char*)d_ws;
  u16* Qs   = (u16*)(ws);                       // 4 MB
  u16* Ks   = (u16*)(ws + (4u  << 20));         // 4 MB
  u16* Vs   = (u16*)(ws + (8u  << 20));         // 4 MB
  u16* Vt   = (u16*)(ws + (12u << 20));         // 4 MB
  u16* ctx  = (u16*)(ws + (16u << 20));         // 4 MB
  float* tmp = (float*)(ws + (20u << 20));      // 8 MB
  float* out = (float*)d_out;

  proj3_kernel<<<dim3(64, 8, 3), 256, 0, stream>>>(Q, K, V, WQ, WK, WV, bQ, bK, bV, Qs, Ks, Vs);
  transpose_v_kernel<<<dim3(64, 8), 256, 0, stream>>>(Vs, Vt);
  attn_kernel<<<dim3(64, 8), 256, 0, stream>>>(Qs, Ks, Vt, ctx);
  gemmo_kernel<<<dim3(64, 8), 256, 0, stream>>>(ctx, WO, bO, Q, tmp);
  ln_kernel<<<1024, 256, 0, stream>>>(tmp, gamma, beta, out);
}

// Round 2
// 219.266 us; speedup vs baseline: 1.3125x; 1.3125x over previous
//
#include <hip/hip_runtime.h>
#include <cstdint>

#define N_TOK 4096
#define DMODEL 512
#define NHEADS 8
#define HDIM 64

typedef unsigned short u16;
typedef __bf16 bf16x8 __attribute__((ext_vector_type(8)));
typedef float f32x4 __attribute__((ext_vector_type(4)));

union U128 { uint4 u; bf16x8 b; u16 s[8]; };

__device__ __forceinline__ u16 f2bf(float f) {           // RNE
  uint32_t u = __builtin_bit_cast(uint32_t, f);
  u += 0x7FFFu + ((u >> 16) & 1u);
  return (u16)(u >> 16);
}
__device__ __forceinline__ u16 bfr(float f) {            // round-half-up (p>=0)
  uint32_t u = __builtin_bit_cast(uint32_t, f);
  return (u16)((u + 0x8000u) >> 16);
}
__device__ __forceinline__ float bf2f(u16 s) {
  uint32_t u = ((uint32_t)s) << 16;
  return __builtin_bit_cast(float, u);
}

#if __has_builtin(__builtin_amdgcn_exp2f)
#define EXP2(x) __builtin_amdgcn_exp2f(x)
#else
#define EXP2(x) __expf((x) * 0.6931471805599453f)
#endif

// async global->LDS, 16B/lane, dest = wave-uniform base + lane*16
__device__ __forceinline__ void ldg2lds16(const void* g, void* s) {
  __builtin_amdgcn_global_load_lds(
      (const __attribute__((address_space(1))) void*)g,
      (__attribute__((address_space(3))) void*)s, 16, 0, 0);
}

// ---------------------------------------------------------------------------
// Kernel 0: fp32 -> bf16 pre-convert (7 arrays selected by blockIdx.y)
// ---------------------------------------------------------------------------
__global__ __launch_bounds__(256) void cvt7_kernel(
    const float* __restrict__ a0, const float* __restrict__ a1, const float* __restrict__ a2,
    const float* __restrict__ a3, const float* __restrict__ a4, const float* __restrict__ a5,
    const float* __restrict__ a6,
    u16* __restrict__ b0, u16* __restrict__ b1, u16* __restrict__ b2,
    u16* __restrict__ b3, u16* __restrict__ b4, u16* __restrict__ b5,
    u16* __restrict__ b6)
{
  const float* src; u16* dst; int sz;
  switch (blockIdx.y) {
    case 0: src = a0; dst = b0; sz = N_TOK * DMODEL; break;
    case 1: src = a1; dst = b1; sz = N_TOK * DMODEL; break;
    case 2: src = a2; dst = b2; sz = N_TOK * DMODEL; break;
    case 3: src = a3; dst = b3; sz = DMODEL * DMODEL; break;
    case 4: src = a4; dst = b4; sz = DMODEL * DMODEL; break;
    case 5: src = a5; dst = b5; sz = DMODEL * DMODEL; break;
    default: src = a6; dst = b6; sz = DMODEL * DMODEL; break;
  }
  int i = (blockIdx.x * 256 + threadIdx.x) * 4;
  if (i >= sz) return;
  float4 f = *(const float4*)(src + i);
  ushort4 o;
  o.x = f2bf(f.x); o.y = f2bf(f.y); o.z = f2bf(f.z); o.w = f2bf(f.w);
  *(ushort4*)(dst + i) = o;
}

// ---------------------------------------------------------------------------
// Kernel 1: fused QKV projection (bf16 in, bf16 out), 64x64 tile, BK=64
// grid (64, 8, 3), block 256
// ---------------------------------------------------------------------------
__global__ __launch_bounds__(256) void proj3_kernel(
    const u16* __restrict__ Qb, const u16* __restrict__ Kb, const u16* __restrict__ Vb,
    const u16* __restrict__ WQ, const u16* __restrict__ WK, const u16* __restrict__ WV,
    const float* __restrict__ bQ, const float* __restrict__ bK, const float* __restrict__ bV,
    u16* __restrict__ Qs, u16* __restrict__ Ks, u16* __restrict__ Vs)
{
  const int z = blockIdx.z;
  const u16* A      = (z == 0) ? Qb : (z == 1) ? Kb : Vb;
  const u16* W      = (z == 0) ? WQ : (z == 1) ? WK : WV;
  const float* bias = (z == 0) ? bQ : (z == 1) ? bK : bV;
  u16* Y            = (z == 0) ? Qs : (z == 1) ? Ks : Vs;

  const int m0 = blockIdx.x * 64;
  const int j0 = blockIdx.y * 64;
  const int tid = threadIdx.x;
  const int w = tid >> 6, lane = tid & 63, quad = lane >> 4, l = lane & 15;

  __shared__ bf16x8 sA[8][64];   // [d-chunk of 8][row]
  __shared__ bf16x8 sB[8][64];

  const f32x4 zero = {0.f, 0.f, 0.f, 0.f};
  f32x4 acc[4];
  for (int s = 0; s < 4; ++s) acc[s] = zero;

  for (int k0 = 0; k0 < DMODEL; k0 += 64) {
    __syncthreads();
    {
      const u16* ag = A + (size_t)(m0 + lane) * DMODEL + k0 + w * 16;
      ldg2lds16(ag,     (char*)sA + (2 * w) * 1024);
      ldg2lds16(ag + 8, (char*)sA + (2 * w + 1) * 1024);
      const u16* bg = W + (size_t)(j0 + lane) * DMODEL + k0 + w * 16;
      ldg2lds16(bg,     (char*)sB + (2 * w) * 1024);
      ldg2lds16(bg + 8, (char*)sB + (2 * w + 1) * 1024);
    }
    __syncthreads();
#pragma unroll
    for (int c = 0; c < 2; ++c) {
      bf16x8 af = sA[c * 4 + quad][w * 16 + l];
#pragma unroll
      for (int s = 0; s < 4; ++s) {
        bf16x8 bfb = sB[c * 4 + quad][s * 16 + l];
        acc[s] = __builtin_amdgcn_mfma_f32_16x16x32_bf16(af, bfb, acc[s], 0, 0, 0);
      }
    }
  }
#pragma unroll
  for (int s = 0; s < 4; ++s) {
    int j = j0 + s * 16 + l;
    float bv = bias[j];
#pragma unroll
    for (int r = 0; r < 4; ++r) {
      int n = m0 + w * 16 + quad * 4 + r;
      Y[(size_t)n * DMODEL + j] = f2bf(acc[s][r] + bv);
    }
  }
}

// ---------------------------------------------------------------------------
// Kernel 2: per-head transpose Vs[n][h*64+vd] -> Vt[h][vd][n]
// ---------------------------------------------------------------------------
__global__ __launch_bounds__(256) void transpose_v_kernel(
    const u16* __restrict__ Vs, u16* __restrict__ Vt)
{
  const int h = blockIdx.y, n0 = blockIdx.x * 64;
  const int tid = threadIdx.x;
  __shared__ u16 tile[64 * 65];
#pragma unroll
  for (int i = 0; i < 2; ++i) {
    int idx = tid + 256 * i;
    int r = idx >> 3, cc = idx & 7;
    U128 u;
    u.u = *(const uint4*)(Vs + (size_t)(n0 + r) * DMODEL + h * HDIM + cc * 8);
#pragma unroll
    for (int j = 0; j < 8; ++j) tile[r * 65 + cc * 8 + j] = u.s[j];
  }
  __syncthreads();
#pragma unroll
  for (int i = 0; i < 2; ++i) {
    int idx = tid + 256 * i;
    int vd = idx >> 3, nc = idx & 7;
    U128 u;
#pragma unroll
    for (int j = 0; j < 8; ++j) u.s[j] = tile[(nc * 8 + j) * 65 + vd];
    *(uint4*)(Vt + (size_t)h * HDIM * N_TOK + (size_t)vd * N_TOK + n0 + nc * 8) = u.u;
  }
}

// ---------------------------------------------------------------------------
// Kernel 3: flash attention, S^T = K.Q^T form, fixed-max softmax, split-K x4.
// grid (64 q-tiles, 8 heads, 4 splits), block 256 (4 waves x 16 queries)
// Writes unnormalized fp32 partial O + partial l.
// ---------------------------------------------------------------------------
__global__ __launch_bounds__(256) void attn_kernel(
    const u16* __restrict__ Qs, const u16* __restrict__ Ks,
    const u16* __restrict__ Vt, float* __restrict__ Opart, float* __restrict__ Lpart)
{
  const int qt = blockIdx.x, h = blockIdx.y, split = blockIdx.z;
  const int q0 = qt * 64;
  const int tid = threadIdx.x;
  const int w = tid >> 6, lane = tid & 63, quad = lane >> 4, l = lane & 15;

  __shared__ bf16x8 kch[8][64];                  // [d-chunk][key]
  __shared__ bf16x8 vch[8][64];                  // [key-chunk][vd]
  __shared__ __align__(16) u16 pbuf[4][16][72];  // [wave][query][key], stride 72

  // Q as B-fragment: lane holds Q[query=w*16+l][d=c*32+quad*8+j], scaled by log2e/8
  bf16x8 qf[2];
#pragma unroll
  for (int c = 0; c < 2; ++c) {
    U128 u;
    u.u = *(const uint4*)(Qs + (size_t)(q0 + w * 16 + l) * DMODEL + h * HDIM + c * 32 + quad * 8);
#pragma unroll
    for (int j = 0; j < 8; ++j) u.s[j] = f2bf(bf2f(u.s[j]) * 0.18033688f);
    qf[c] = u.b;
  }

  const f32x4 zero = {0.f, 0.f, 0.f, 0.f};
  f32x4 o[4];
#pragma unroll
  for (int s = 0; s < 4; ++s) o[s] = zero;
  float lsum = 0.f;

  for (int it = 0; it < 16; ++it) {
    const int j0 = split * 1024 + it * 64;
    __syncthreads();
    {
      const u16* kg = Ks + (size_t)(j0 + lane) * DMODEL + h * HDIM + w * 16;
      ldg2lds16(kg,     (char*)kch + (2 * w) * 1024);
      ldg2lds16(kg + 8, (char*)kch + (2 * w + 1) * 1024);
      const u16* vg = Vt + (size_t)h * HDIM * N_TOK + (size_t)lane * N_TOK + j0 + w * 16;
      ldg2lds16(vg,     (char*)vch + (2 * w) * 1024);
      ldg2lds16(vg + 8, (char*)vch + (2 * w + 1) * 1024);
    }
    __syncthreads();

    // S^T = K.Q^T : lane holds scores for query l, keys t*16+quad*4+r
    f32x4 sacc[4];
#pragma unroll
    for (int t = 0; t < 4; ++t) sacc[t] = zero;
#pragma unroll
    for (int c = 0; c < 2; ++c) {
#pragma unroll
      for (int t = 0; t < 4; ++t) {
        bf16x8 kf = kch[c * 4 + quad][t * 16 + l];
        sacc[t] = __builtin_amdgcn_mfma_f32_16x16x32_bf16(kf, qf[c], sacc[t], 0, 0, 0);
      }
    }

    // fixed-max softmax partial: p = 2^s (s pre-scaled), in-lane accumulation
#pragma unroll
    for (int t = 0; t < 4; ++t) {
      float p0 = EXP2(sacc[t][0]);
      float p1 = EXP2(sacc[t][1]);
      float p2 = EXP2(sacc[t][2]);
      float p3 = EXP2(sacc[t][3]);
      lsum += (p0 + p1) + (p2 + p3);
      ushort4 pk;
      pk.x = bfr(p0); pk.y = bfr(p1); pk.z = bfr(p2); pk.w = bfr(p3);
      *(ushort4*)&pbuf[w][l][t * 16 + quad * 4] = pk;   // per-wave, no barrier needed
    }

    // O += P.V : A-frag = pbuf row l, keys c*32+quad*8..+7 (contiguous 16B)
#pragma unroll
    for (int c = 0; c < 2; ++c) {
      U128 u;
      u.u = *(const uint4*)&pbuf[w][l][c * 32 + quad * 8];
      bf16x8 pf = u.b;
#pragma unroll
      for (int s = 0; s < 4; ++s) {
        bf16x8 vf = vch[c * 4 + quad][s * 16 + l];
        o[s] = __builtin_amdgcn_mfma_f32_16x16x32_bf16(pf, vf, o[s], 0, 0, 0);
      }
    }
  }

  // reduce l over the 4 quads holding query l's key-slices
  lsum += __shfl_xor(lsum, 16);
  lsum += __shfl_xor(lsum, 32);
  if (quad == 0)
    Lpart[((size_t)split * NHEADS + h) * N_TOK + q0 + w * 16 + l] = lsum;

  float* Ob = Opart + (size_t)(((split * NHEADS + h) * 64) + qt) * 4096;
#pragma unroll
  for (int s = 0; s < 4; ++s)
#pragma unroll
    for (int r = 0; r < 4; ++r)
      Ob[(w * 16 + quad * 4 + r) * 64 + s * 16 + l] = o[s][r];
}

// ---------------------------------------------------------------------------
// Kernel 4: combine split-K partials -> ctx bf16.  1024 blocks x 256 threads.
// ---------------------------------------------------------------------------
__global__ __launch_bounds__(256) void combine_kernel(
    const float* __restrict__ Opart, const float* __restrict__ Lpart,
    u16* __restrict__ ctx)
{
  int idx = blockIdx.x * 256 + threadIdx.x;   // covers 4096*512/8
  int n = idx >> 6;
  int c8 = idx & 63;
  int h = c8 >> 3;
  int vd0 = (c8 & 7) * 8;
  int qt = n >> 6, qin = n & 63;

  float acc[8] = {0, 0, 0, 0, 0, 0, 0, 0};
  float lsum = 0.f;
#pragma unroll
  for (int s = 0; s < 4; ++s) {
    size_t base = (size_t)(((s * NHEADS + h) * 64) + qt) * 4096 + qin * 64 + vd0;
    float4 a = *(const float4*)(Opart + base);
    float4 b = *(const float4*)(Opart + base + 4);
    acc[0] += a.x; acc[1] += a.y; acc[2] += a.z; acc[3] += a.w;
    acc[4] += b.x; acc[5] += b.y; acc[6] += b.z; acc[7] += b.w;
    lsum += Lpart[((size_t)s * NHEADS + h) * N_TOK + n];
  }
  float inv = 1.f / lsum;
  U128 u;
#pragma unroll
  for (int j = 0; j < 8; ++j) u.s[j] = f2bf(acc[j] * inv);
  *(uint4*)(ctx + (size_t)n * DMODEL + h * HDIM + vd0) = u.u;
}

// ---------------------------------------------------------------------------
// Kernel 5: output projection + bias + residual (fp32 out), BK=64
// ---------------------------------------------------------------------------
__global__ __launch_bounds__(256) void gemmo_kernel(
    const u16* __restrict__ ctx, const u16* __restrict__ WO,
    const float* __restrict__ bO, const float* __restrict__ resid,
    float* __restrict__ Y)
{
  const int m0 = blockIdx.x * 64;
  const int j0 = blockIdx.y * 64;
  const int tid = threadIdx.x;
  const int w = tid >> 6, lane = tid & 63, quad = lane >> 4, l = lane & 15;

  __shared__ bf16x8 sA[8][64];
  __shared__ bf16x8 sB[8][64];

  const f32x4 zero = {0.f, 0.f, 0.f, 0.f};
  f32x4 acc[4];
  for (int s = 0; s < 4; ++s) acc[s] = zero;

  for (int k0 = 0; k0 < DMODEL; k0 += 64) {
    __syncthreads();
    {
      const u16* ag = ctx + (size_t)(m0 + lane) * DMODEL + k0 + w * 16;
      ldg2lds16(ag,     (char*)sA + (2 * w) * 1024);
      ldg2lds16(ag + 8, (char*)sA + (2 * w + 1) * 1024);
      const u16* bg = WO + (size_t)(j0 + lane) * DMODEL + k0 + w * 16;
      ldg2lds16(bg,     (char*)sB + (2 * w) * 1024);
      ldg2lds16(bg + 8, (char*)sB + (2 * w + 1) * 1024);
    }
    __syncthreads();
#pragma unroll
    for (int c = 0; c < 2; ++c) {
      bf16x8 af = sA[c * 4 + quad][w * 16 + l];
#pragma unroll
      for (int s = 0; s < 4; ++s) {
        bf16x8 bfb = sB[c * 4 + quad][s * 16 + l];
        acc[s] = __builtin_amdgcn_mfma_f32_16x16x32_bf16(af, bfb, acc[s], 0, 0, 0);
      }
    }
  }
#pragma unroll
  for (int s = 0; s < 4; ++s) {
    int j = j0 + s * 16 + l;
    float bv = bO[j];
#pragma unroll
    for (int r = 0; r < 4; ++r) {
      int n = m0 + w * 16 + quad * 4 + r;
      Y[(size_t)n * DMODEL + j] = acc[s][r] + bv + resid[(size_t)n * DMODEL + j];
    }
  }
}

// ---------------------------------------------------------------------------
// Kernel 6: LayerNorm, one wave per row
// ---------------------------------------------------------------------------
__global__ __launch_bounds__(256) void ln_kernel(
    const float* __restrict__ X, const float* __restrict__ gamma,
    const float* __restrict__ beta, float* __restrict__ Y)
{
  const int w = threadIdx.x >> 6, lane = threadIdx.x & 63;
  const int row = blockIdx.x * 4 + w;
  const float* x = X + (size_t)row * DMODEL + lane * 8;
  float4 a = *(const float4*)x;
  float4 b = *(const float4*)(x + 4);

  float s = a.x + a.y + a.z + a.w + b.x + b.y + b.z + b.w;
#pragma unroll
  for (int m = 1; m < 64; m <<= 1) s += __shfl_xor(s, m);
  float mu = s * (1.f / DMODEL);

  float d0 = a.x - mu, d1 = a.y - mu, d2 = a.z - mu, d3 = a.w - mu;
  float d4 = b.x - mu, d5 = b.y - mu, d6 = b.z - mu, d7 = b.w - mu;
  float v = d0*d0 + d1*d1 + d2*d2 + d3*d3 + d4*d4 + d5*d5 + d6*d6 + d7*d7;
#pragma unroll
  for (int m = 1; m < 64; m <<= 1) v += __shfl_xor(v, m);
  float sc = rsqrtf(v * (1.f / DMODEL) + 1e-5f);

  const float* g = gamma + lane * 8;
  const float* be = beta + lane * 8;
  float4 go = *(const float4*)g;
  float4 g1 = *(const float4*)(g + 4);
  float4 bo = *(const float4*)be;
  float4 b1 = *(const float4*)(be + 4);

  float4 y0, y1;
  y0.x = d0 * sc * go.x + bo.x;  y0.y = d1 * sc * go.y + bo.y;
  y0.z = d2 * sc * go.z + bo.z;  y0.w = d3 * sc * go.w + bo.w;
  y1.x = d4 * sc * g1.x + b1.x;  y1.y = d5 * sc * g1.y + b1.y;
  y1.z = d6 * sc * g1.z + b1.z;  y1.w = d7 * sc * g1.w + b1.w;

  float* yp = Y + (size_t)row * DMODEL + lane * 8;
  *(float4*)yp = y0;
  *(float4*)(yp + 4) = y1;
}

// ---------------------------------------------------------------------------
extern "C" void kernel_launch(void* const* d_in, const int* in_sizes, int n_in,
                              void* d_out, int out_size, void* d_ws, size_t ws_size,
                              hipStream_t stream)
{
  const float* Q     = (const float*)d_in[0];
  const float* K     = (const float*)d_in[1];
  const float* V     = (const float*)d_in[2];
  const float* WQ    = (const float*)d_in[3];
  const float* bQ    = (const float*)d_in[4];
  const float* WK    = (const float*)d_in[5];
  const float* bK    = (const float*)d_in[6];
  const float* WV    = (const float*)d_in[7];
  const float* bV    = (const float*)d_in[8];
  const float* WO    = (const float*)d_in[9];
  const float* bO    = (const float*)d_in[10];
  const float* gamma = (const float*)d_in[11];
  const float* beta  = (const float*)d_in[12];

  const size_t MB = 1ull << 20;
  char* ws = (char*)d_ws;
  u16* Qb   = (u16*)(ws + 0 * MB);            // 4 MB each
  u16* Kb   = (u16*)(ws + 4 * MB);
  u16* Vb   = (u16*)(ws + 8 * MB);
  u16* WQb  = (u16*)(ws + 12 * MB);           // 0.5 MB each
  u16* WKb  = (u16*)(ws + 12 * MB + 512 * 1024);
  u16* WVb  = (u16*)(ws + 13 * MB);
  u16* WOb  = (u16*)(ws + 13 * MB + 512 * 1024);
  u16* Qs   = (u16*)(ws + 14 * MB);
  u16* Ks   = (u16*)(ws + 18 * MB);
  u16* Vs   = (u16*)(ws + 22 * MB);
  u16* Vt   = (u16*)(ws + 26 * MB);
  u16* ctx  = (u16*)(ws + 30 * MB);
  float* Opart = (float*)(ws + 34 * MB);      // 32 MB (dead after combine)
  float* tmp   = (float*)(ws + 34 * MB);      // 8 MB, overlays Opart (disjoint lifetime)
  float* Lpart = (float*)(ws + 66 * MB);      // 0.5 MB
  float* out = (float*)d_out;

  cvt7_kernel<<<dim3(2048, 7), 256, 0, stream>>>(Q, K, V, WQ, WK, WV, WO,
                                                 Qb, Kb, Vb, WQb, WKb, WVb, WOb);
  proj3_kernel<<<dim3(64, 8, 3), 256, 0, stream>>>(Qb, Kb, Vb, WQb, WKb, WVb,
                                                   bQ, bK, bV, Qs, Ks, Vs);
  transpose_v_kernel<<<dim3(64, 8), 256, 0, stream>>>(Vs, Vt);
  attn_kernel<<<dim3(64, 8, 4), 256, 0, stream>>>(Qs, Ks, Vt, Opart, Lpart);
  combine_kernel<<<1024, 256, 0, stream>>>(Opart, Lpart, ctx);
  gemmo_kernel<<<dim3(64, 8), 256, 0, stream>>>(ctx, WOb, bO, Q, tmp);
  ln_kernel<<<1024, 256, 0, stream>>>(tmp, gamma, beta, out);
}

// Round 3
// 187.497 us; speedup vs baseline: 1.5349x; 1.1694x over previous
//
#include <hip/hip_runtime.h>
#include <cstdint>

#define N_TOK 4096
#define DMODEL 512
#define NHEADS 8
#define HDIM 64

typedef unsigned short u16;
typedef __bf16 bf16x8 __attribute__((ext_vector_type(8)));
typedef float f32x4 __attribute__((ext_vector_type(4)));

union U128 { uint4 u; bf16x8 b; u16 s[8]; };

__device__ __forceinline__ u16 f2bf(float f) {           // RNE
  uint32_t u = __builtin_bit_cast(uint32_t, f);
  u += 0x7FFFu + ((u >> 16) & 1u);
  return (u16)(u >> 16);
}
__device__ __forceinline__ u16 bfr(float f) {            // round-half-up (p>=0)
  uint32_t u = __builtin_bit_cast(uint32_t, f);
  return (u16)((u + 0x8000u) >> 16);
}
__device__ __forceinline__ float bf2f(u16 s) {
  uint32_t u = ((uint32_t)s) << 16;
  return __builtin_bit_cast(float, u);
}

#if __has_builtin(__builtin_amdgcn_exp2f)
#define EXP2(x) __builtin_amdgcn_exp2f(x)
#else
#define EXP2(x) __expf((x) * 0.6931471805599453f)
#endif

// async global->LDS, 16B/lane, dest = wave-uniform base + lane*16
__device__ __forceinline__ void ldg2lds16(const void* g, void* s) {
  __builtin_amdgcn_global_load_lds(
      (const __attribute__((address_space(1))) void*)g,
      (__attribute__((address_space(3))) void*)s, 16, 0, 0);
}

// ---------------------------------------------------------------------------
// Kernel 0: fp32 -> bf16 pre-convert of Q,K,V.  grid (2048, 3) x 256.
// ---------------------------------------------------------------------------
__global__ __launch_bounds__(256) void cvt3_kernel(
    const float* __restrict__ a0, const float* __restrict__ a1, const float* __restrict__ a2,
    u16* __restrict__ b0, u16* __restrict__ b1, u16* __restrict__ b2)
{
  const float* src = (blockIdx.y == 0) ? a0 : (blockIdx.y == 1) ? a1 : a2;
  u16* dst         = (blockIdx.y == 0) ? b0 : (blockIdx.y == 1) ? b1 : b2;
  int i = (blockIdx.x * 256 + threadIdx.x) * 4;
  float4 f = *(const float4*)(src + i);
  ushort4 o;
  o.x = f2bf(f.x); o.y = f2bf(f.y); o.z = f2bf(f.z); o.w = f2bf(f.w);
  *(ushort4*)(dst + i) = o;
}

// ---------------------------------------------------------------------------
// Kernel 1: fused QKV projection, 128x64 tile, m=2 reuse, inline W convert.
// V branch writes V^T directly (Vt[j][n]).  grid (32, 8, 3), block 256.
// ---------------------------------------------------------------------------
__global__ __launch_bounds__(256) void proj3_kernel(
    const u16* __restrict__ Qb, const u16* __restrict__ Kb, const u16* __restrict__ Vb,
    const float* __restrict__ WQ, const float* __restrict__ WK, const float* __restrict__ WV,
    const float* __restrict__ bQ, const float* __restrict__ bK, const float* __restrict__ bV,
    u16* __restrict__ Qs, u16* __restrict__ Ks, u16* __restrict__ Vt)
{
  const int z = blockIdx.z;
  const u16* A      = (z == 0) ? Qb : (z == 1) ? Kb : Vb;
  const float* W    = (z == 0) ? WQ : (z == 1) ? WK : WV;
  const float* bias = (z == 0) ? bQ : (z == 1) ? bK : bV;

  const int m0 = blockIdx.x * 128;
  const int j0 = blockIdx.y * 64;
  const int tid = threadIdx.x;
  const int w = tid >> 6, lane = tid & 63, quad = lane >> 4, l = lane & 15;

  __shared__ bf16x8 sA[8][128];  // [d-chunk][row], 16 KB
  __shared__ bf16x8 sB[8][64];   // 8 KB

  const f32x4 zero = {0.f, 0.f, 0.f, 0.f};
  f32x4 acc[2][4];
#pragma unroll
  for (int m = 0; m < 2; ++m)
#pragma unroll
    for (int s = 0; s < 4; ++s) acc[m][s] = zero;

  const int brow0 = tid >> 3;   // 0..31
  const int bc    = tid & 7;    // 0..7

  for (int k0 = 0; k0 < DMODEL; k0 += 64) {
    __syncthreads();
    // A: 8 chunks x 128 rows via global_load_lds (4 per wave)
#pragma unroll
    for (int i = 0; i < 4; ++i) {
      const int chunk = 2 * w + (i >> 1), half = (i & 1) * 64;
      const u16* ag = A + (size_t)(m0 + half + lane) * DMODEL + k0 + chunk * 8;
      ldg2lds16(ag, (char*)sA + (size_t)(chunk * 128 + half) * 16);
    }
    // B: inline fp32->bf16 convert, coalesced (8 threads cover 256B)
#pragma unroll
    for (int i = 0; i < 2; ++i) {
      const int row = brow0 + 32 * i;
      const float* wp = W + (size_t)(j0 + row) * DMODEL + k0 + bc * 8;
      float4 g0 = *(const float4*)wp;
      float4 g1 = *(const float4*)(wp + 4);
      U128 v;
      v.s[0]=f2bf(g0.x); v.s[1]=f2bf(g0.y); v.s[2]=f2bf(g0.z); v.s[3]=f2bf(g0.w);
      v.s[4]=f2bf(g1.x); v.s[5]=f2bf(g1.y); v.s[6]=f2bf(g1.z); v.s[7]=f2bf(g1.w);
      sB[bc][row] = v.b;
    }
    __syncthreads();
#pragma unroll
    for (int c = 0; c < 2; ++c) {
      bf16x8 af0 = sA[c * 4 + quad][w * 32 + l];
      bf16x8 af1 = sA[c * 4 + quad][w * 32 + 16 + l];
#pragma unroll
      for (int s = 0; s < 4; ++s) {
        bf16x8 bfb = sB[c * 4 + quad][s * 16 + l];
        acc[0][s] = __builtin_amdgcn_mfma_f32_16x16x32_bf16(af0, bfb, acc[0][s], 0, 0, 0);
        acc[1][s] = __builtin_amdgcn_mfma_f32_16x16x32_bf16(af1, bfb, acc[1][s], 0, 0, 0);
      }
    }
  }

#pragma unroll
  for (int m = 0; m < 2; ++m)
#pragma unroll
    for (int s = 0; s < 4; ++s) {
      int j = j0 + s * 16 + l;
      float bv = bias[j];
      int n0 = m0 + w * 32 + m * 16 + quad * 4;
      if (z < 2) {
        u16* Y = (z == 0) ? Qs : Ks;
#pragma unroll
        for (int r = 0; r < 4; ++r)
          Y[(size_t)(n0 + r) * DMODEL + j] = f2bf(acc[m][s][r] + bv);
      } else {
        ushort4 pk;
        pk.x = f2bf(acc[m][s][0] + bv); pk.y = f2bf(acc[m][s][1] + bv);
        pk.z = f2bf(acc[m][s][2] + bv); pk.w = f2bf(acc[m][s][3] + bv);
        *(ushort4*)(Vt + (size_t)j * N_TOK + n0) = pk;   // V^T write
      }
    }
}

// ---------------------------------------------------------------------------
// Kernel 2: flash attention, S^T = K.Q^T, fixed-max softmax, split-K x4,
// 8 waves x 32 queries = 256 q/block.  grid (16, 8, 4), block 512.
// ---------------------------------------------------------------------------
__global__ __launch_bounds__(512, 4) void attn_kernel(
    const u16* __restrict__ Qs, const u16* __restrict__ Ks,
    const u16* __restrict__ Vt, float* __restrict__ Opart, float* __restrict__ Lpart)
{
  const int qt = blockIdx.x, h = blockIdx.y, split = blockIdx.z;
  const int tid = threadIdx.x;
  const int w = tid >> 6, lane = tid & 63, quad = lane >> 4, l = lane & 15;

  __shared__ bf16x8 kch[8][64];                  // [d-chunk][key]   8 KB
  __shared__ bf16x8 vch[8][64];                  // [key-chunk][vd]  8 KB
  __shared__ __align__(16) u16 pbuf[8][32][72];  // [wave][q][key]  36 KB

  const int wq0 = qt * 256 + w * 32;

  // Q fragments (B-operand), pre-scaled by log2(e)/8
  bf16x8 qf[2][2];
#pragma unroll
  for (int c = 0; c < 2; ++c)
#pragma unroll
    for (int m = 0; m < 2; ++m) {
      U128 u;
      u.u = *(const uint4*)(Qs + (size_t)(wq0 + m * 16 + l) * DMODEL + h * HDIM + c * 32 + quad * 8);
#pragma unroll
      for (int j = 0; j < 8; ++j) u.s[j] = f2bf(bf2f(u.s[j]) * 0.18033688f);
      qf[c][m] = u.b;
    }

  const f32x4 zero = {0.f, 0.f, 0.f, 0.f};
  f32x4 o[2][4];
  float lsum[2] = {0.f, 0.f};
#pragma unroll
  for (int m = 0; m < 2; ++m)
#pragma unroll
    for (int s = 0; s < 4; ++s) o[m][s] = zero;

  for (int it = 0; it < 16; ++it) {
    const int j0 = split * 1024 + it * 64;
    __syncthreads();
    if (w < 4) {            // waves 0-3 stage K (8 KB)
      const u16* kg = Ks + (size_t)(j0 + lane) * DMODEL + h * HDIM + w * 16;
      ldg2lds16(kg,     (char*)kch + w * 2048);
      ldg2lds16(kg + 8, (char*)kch + w * 2048 + 1024);
    } else {                // waves 4-7 stage V^T (8 KB)
      const int w2 = w - 4;
      const u16* vg = Vt + (size_t)(h * HDIM + lane) * N_TOK + j0 + w2 * 16;
      ldg2lds16(vg,     (char*)vch + w2 * 2048);
      ldg2lds16(vg + 8, (char*)vch + w2 * 2048 + 1024);
    }
    __syncthreads();

    // S^T = K.Q^T : each kf read feeds 2 MFMAs (query subtiles)
    f32x4 sacc[2][4];
#pragma unroll
    for (int m = 0; m < 2; ++m)
#pragma unroll
      for (int t = 0; t < 4; ++t) sacc[m][t] = zero;
#pragma unroll
    for (int c = 0; c < 2; ++c) {
#pragma unroll
      for (int t = 0; t < 4; ++t) {
        bf16x8 kf = kch[c * 4 + quad][t * 16 + l];
        sacc[0][t] = __builtin_amdgcn_mfma_f32_16x16x32_bf16(kf, qf[c][0], sacc[0][t], 0, 0, 0);
        sacc[1][t] = __builtin_amdgcn_mfma_f32_16x16x32_bf16(kf, qf[c][1], sacc[1][t], 0, 0, 0);
      }
    }

    // fixed-max softmax partials, in-lane; pack P to per-wave LDS
#pragma unroll
    for (int m = 0; m < 2; ++m) {
#pragma unroll
      for (int t = 0; t < 4; ++t) {
        float p0 = EXP2(sacc[m][t][0]);
        float p1 = EXP2(sacc[m][t][1]);
        float p2 = EXP2(sacc[m][t][2]);
        float p3 = EXP2(sacc[m][t][3]);
        lsum[m] += (p0 + p1) + (p2 + p3);
        ushort4 pk;
        pk.x = bfr(p0); pk.y = bfr(p1); pk.z = bfr(p2); pk.w = bfr(p3);
        *(ushort4*)&pbuf[w][m * 16 + l][t * 16 + quad * 4] = pk;
      }
    }

    // O += P.V : each vf read feeds 2 MFMAs
#pragma unroll
    for (int c = 0; c < 2; ++c) {
      U128 u0, u1;
      u0.u = *(const uint4*)&pbuf[w][l][c * 32 + quad * 8];
      u1.u = *(const uint4*)&pbuf[w][16 + l][c * 32 + quad * 8];
#pragma unroll
      for (int s = 0; s < 4; ++s) {
        bf16x8 vf = vch[c * 4 + quad][s * 16 + l];
        o[0][s] = __builtin_amdgcn_mfma_f32_16x16x32_bf16(u0.b, vf, o[0][s], 0, 0, 0);
        o[1][s] = __builtin_amdgcn_mfma_f32_16x16x32_bf16(u1.b, vf, o[1][s], 0, 0, 0);
      }
    }
  }

#pragma unroll
  for (int m = 0; m < 2; ++m) {
    lsum[m] += __shfl_xor(lsum[m], 16);
    lsum[m] += __shfl_xor(lsum[m], 32);
  }
  if (quad == 0) {
    Lpart[((size_t)split * NHEADS + h) * N_TOK + wq0 + l]      = lsum[0];
    Lpart[((size_t)split * NHEADS + h) * N_TOK + wq0 + 16 + l] = lsum[1];
  }
  float* Ob = Opart + (size_t)((split * NHEADS + h) * 16 + qt) * 16384;
#pragma unroll
  for (int m = 0; m < 2; ++m)
#pragma unroll
    for (int s = 0; s < 4; ++s)
#pragma unroll
      for (int r = 0; r < 4; ++r)
        Ob[(w * 32 + m * 16 + quad * 4 + r) * 64 + s * 16 + l] = o[m][s][r];
}

// ---------------------------------------------------------------------------
// Kernel 3: combine split-K partials -> ctx bf16.  1024 x 256.
// ---------------------------------------------------------------------------
__global__ __launch_bounds__(256) void combine_kernel(
    const float* __restrict__ Opart, const float* __restrict__ Lpart,
    u16* __restrict__ ctx)
{
  int idx = blockIdx.x * 256 + threadIdx.x;
  int n = idx >> 6;
  int c8 = idx & 63;
  int h = c8 >> 3;
  int vd0 = (c8 & 7) * 8;
  int qt = n >> 8, qin = n & 255;

  float acc[8] = {0, 0, 0, 0, 0, 0, 0, 0};
  float lsum = 0.f;
#pragma unroll
  for (int s = 0; s < 4; ++s) {
    size_t base = (size_t)((s * NHEADS + h) * 16 + qt) * 16384 + qin * 64 + vd0;
    float4 a = *(const float4*)(Opart + base);
    float4 b = *(const float4*)(Opart + base + 4);
    acc[0] += a.x; acc[1] += a.y; acc[2] += a.z; acc[3] += a.w;
    acc[4] += b.x; acc[5] += b.y; acc[6] += b.z; acc[7] += b.w;
    lsum += Lpart[((size_t)s * NHEADS + h) * N_TOK + n];
  }
  float inv = 1.f / lsum;
  U128 u;
#pragma unroll
  for (int j = 0; j < 8; ++j) u.s[j] = f2bf(acc[j] * inv);
  *(uint4*)(ctx + (size_t)n * DMODEL + h * HDIM + vd0) = u.u;
}

// ---------------------------------------------------------------------------
// Kernel 4: output projection + bias + residual, inline WO convert.
// grid (64, 8), block 256.
// ---------------------------------------------------------------------------
__global__ __launch_bounds__(256) void gemmo_kernel(
    const u16* __restrict__ ctx, const float* __restrict__ WO,
    const float* __restrict__ bO, const float* __restrict__ resid,
    float* __restrict__ Y)
{
  const int m0 = blockIdx.x * 64;
  const int j0 = blockIdx.y * 64;
  const int tid = threadIdx.x;
  const int w = tid >> 6, lane = tid & 63, quad = lane >> 4, l = lane & 15;

  __shared__ bf16x8 sA[8][64];
  __shared__ bf16x8 sB[8][64];

  const f32x4 zero = {0.f, 0.f, 0.f, 0.f};
  f32x4 acc[4];
  for (int s = 0; s < 4; ++s) acc[s] = zero;

  const int brow0 = tid >> 3;
  const int bc    = tid & 7;

  for (int k0 = 0; k0 < DMODEL; k0 += 64) {
    __syncthreads();
#pragma unroll
    for (int i = 0; i < 2; ++i) {
      const u16* ag = ctx + (size_t)(m0 + lane) * DMODEL + k0 + (2 * w + i) * 8;
      ldg2lds16(ag, (char*)sA + (size_t)(2 * w + i) * 1024);
    }
#pragma unroll
    for (int i = 0; i < 2; ++i) {
      const int row = brow0 + 32 * i;
      const float* wp = WO + (size_t)(j0 + row) * DMODEL + k0 + bc * 8;
      float4 g0 = *(const float4*)wp;
      float4 g1 = *(const float4*)(wp + 4);
      U128 v;
      v.s[0]=f2bf(g0.x); v.s[1]=f2bf(g0.y); v.s[2]=f2bf(g0.z); v.s[3]=f2bf(g0.w);
      v.s[4]=f2bf(g1.x); v.s[5]=f2bf(g1.y); v.s[6]=f2bf(g1.z); v.s[7]=f2bf(g1.w);
      sB[bc][row] = v.b;
    }
    __syncthreads();
#pragma unroll
    for (int c = 0; c < 2; ++c) {
      bf16x8 af = sA[c * 4 + quad][w * 16 + l];
#pragma unroll
      for (int s = 0; s < 4; ++s) {
        bf16x8 bfb = sB[c * 4 + quad][s * 16 + l];
        acc[s] = __builtin_amdgcn_mfma_f32_16x16x32_bf16(af, bfb, acc[s], 0, 0, 0);
      }
    }
  }
#pragma unroll
  for (int s = 0; s < 4; ++s) {
    int j = j0 + s * 16 + l;
    float bv = bO[j];
#pragma unroll
    for (int r = 0; r < 4; ++r) {
      int n = m0 + w * 16 + quad * 4 + r;
      Y[(size_t)n * DMODEL + j] = acc[s][r] + bv + resid[(size_t)n * DMODEL + j];
    }
  }
}

// ---------------------------------------------------------------------------
// Kernel 5: LayerNorm, one wave per row
// ---------------------------------------------------------------------------
__global__ __launch_bounds__(256) void ln_kernel(
    const float* __restrict__ X, const float* __restrict__ gamma,
    const float* __restrict__ beta, float* __restrict__ Y)
{
  const int w = threadIdx.x >> 6, lane = threadIdx.x & 63;
  const int row = blockIdx.x * 4 + w;
  const float* x = X + (size_t)row * DMODEL + lane * 8;
  float4 a = *(const float4*)x;
  float4 b = *(const float4*)(x + 4);

  float s = a.x + a.y + a.z + a.w + b.x + b.y + b.z + b.w;
#pragma unroll
  for (int m = 1; m < 64; m <<= 1) s += __shfl_xor(s, m);
  float mu = s * (1.f / DMODEL);

  float d0 = a.x - mu, d1 = a.y - mu, d2 = a.z - mu, d3 = a.w - mu;
  float d4 = b.x - mu, d5 = b.y - mu, d6 = b.z - mu, d7 = b.w - mu;
  float v = d0*d0 + d1*d1 + d2*d2 + d3*d3 + d4*d4 + d5*d5 + d6*d6 + d7*d7;
#pragma unroll
  for (int m = 1; m < 64; m <<= 1) v += __shfl_xor(v, m);
  float sc = rsqrtf(v * (1.f / DMODEL) + 1e-5f);

  const float* g = gamma + lane * 8;
  const float* be = beta + lane * 8;
  float4 go = *(const float4*)g;
  float4 g1 = *(const float4*)(g + 4);
  float4 bo = *(const float4*)be;
  float4 b1 = *(const float4*)(be + 4);

  float4 y0, y1;
  y0.x = d0 * sc * go.x + bo.x;  y0.y = d1 * sc * go.y + bo.y;
  y0.z = d2 * sc * go.z + bo.z;  y0.w = d3 * sc * go.w + bo.w;
  y1.x = d4 * sc * g1.x + b1.x;  y1.y = d5 * sc * g1.y + b1.y;
  y1.z = d6 * sc * g1.z + b1.z;  y1.w = d7 * sc * g1.w + b1.w;

  float* yp = Y + (size_t)row * DMODEL + lane * 8;
  *(float4*)yp = y0;
  *(float4*)(yp + 4) = y1;
}

// ---------------------------------------------------------------------------
extern "C" void kernel_launch(void* const* d_in, const int* in_sizes, int n_in,
                              void* d_out, int out_size, void* d_ws, size_t ws_size,
                              hipStream_t stream)
{
  const float* Q     = (const float*)d_in[0];
  const float* K     = (const float*)d_in[1];
  const float* V     = (const float*)d_in[2];
  const float* WQ    = (const float*)d_in[3];
  const float* bQ    = (const float*)d_in[4];
  const float* WK    = (const float*)d_in[5];
  const float* bK    = (const float*)d_in[6];
  const float* WV    = (const float*)d_in[7];
  const float* bV    = (const float*)d_in[8];
  const float* WO    = (const float*)d_in[9];
  const float* bO    = (const float*)d_in[10];
  const float* gamma = (const float*)d_in[11];
  const float* beta  = (const float*)d_in[12];

  const size_t MB = 1ull << 20;
  char* ws = (char*)d_ws;
  u16* Qb   = (u16*)(ws + 0 * MB);       // bf16 copies of inputs, 4 MB each
  u16* Kb   = (u16*)(ws + 4 * MB);
  u16* Vb   = (u16*)(ws + 8 * MB);
  u16* Qs   = (u16*)(ws + 12 * MB);      // projected, 4 MB each
  u16* Ks   = (u16*)(ws + 16 * MB);
  u16* Vt   = (u16*)(ws + 20 * MB);      // projected V, transposed [j][n]
  u16* ctx  = (u16*)(ws + 24 * MB);
  float* Opart = (float*)(ws + 28 * MB); // 32 MB (dead after combine)
  float* tmp   = (float*)(ws + 28 * MB); // 8 MB, overlays Opart
  float* Lpart = (float*)(ws + 60 * MB); // 0.5 MB
  float* out = (float*)d_out;

  cvt3_kernel<<<dim3(2048, 3), 256, 0, stream>>>(Q, K, V, Qb, Kb, Vb);
  proj3_kernel<<<dim3(32, 8, 3), 256, 0, stream>>>(Qb, Kb, Vb, WQ, WK, WV,
                                                   bQ, bK, bV, Qs, Ks, Vt);
  attn_kernel<<<dim3(16, 8, 4), 512, 0, stream>>>(Qs, Ks, Vt, Opart, Lpart);
  combine_kernel<<<1024, 256, 0, stream>>>(Opart, Lpart, ctx);
  gemmo_kernel<<<dim3(64, 8), 256, 0, stream>>>(ctx, WO, bO, Q, tmp);
  ln_kernel<<<1024, 256, 0, stream>>>(tmp, gamma, beta, out);
}